// Round 9
// baseline (617.203 us; speedup 1.0000x reference)
//
#include <hip/hip_runtime.h>
#include <math.h>

// x: [1,32,32,32,80] fp32 (80 = 32 scalars + 16 vec*3)
// conv: low-rank kernel basis 12 = 3 radial * {1, Yd, Yh, Yw}
// FUSED conv, producer/consumer: 512-thr blocks (8 waves), 64-voxel tile (2,4,8),
//   2 blocks/CU (LDS 76.3 KB).  10 chunks of 8 ci.  Fixed roles:
//   waves 0-3 = stage A (tap-pair VALU -> zc[c&1]);  waves 4-7 = stage B
//   (split-bf16 MFMA on zc[(c-1)&1]) + halo prefetch/write.  zc double-buffered.
//   Tap table CONSTEXPR (immediate ds offsets, literal coefficients).
// out: [1,64,64,64,80] fp32

typedef __attribute__((ext_vector_type(8))) short bf16x8;
typedef __attribute__((ext_vector_type(4))) float f32x4;
typedef __attribute__((ext_vector_type(4))) unsigned int u32x4;

__device__ __forceinline__ int eps3(int a, int m, int b) {
    if (a == b || a == m || m == b) return 0;
    return ((a==0&&m==1&&b==2)||(a==1&&m==2&&b==0)||(a==2&&m==0&&b==1)) ? 1 : -1;
}

// ---------------------------------------------------------------- constexpr tap table
// halo layout: pos = hd*96 + hh*12 + hw  (6x8x12), row stride 10 floats (8 ci + 2 pad)
struct TapTab {
    int   op[40];        // float-offset, positive rep
    float R[40][3];
    float RY[40][9];
    float Rc[3];
};
constexpr float cexpf_(float x) {
    float y = x * (1.f/16.f);
    float s = 1.f + y*(1.f + y*(0.5f + y*((1.f/6.f) + y*((1.f/24.f) + y*(1.f/120.f)))));
    s *= s; s *= s; s *= s; s *= s;
    return s;
}
constexpr float csqrtf_(float x) {
    float g = x > 1.f ? x : 1.f;
    for (int i = 0; i < 40; i++) g = 0.5f*(g + x/g);
    return g;
}
constexpr TapTab make_taps() {
    TapTab T{};
    int idx = 0;
    for (int t = 0; t < 125; t++) {
        int td = t/25 - 2, th = (t/5)%5 - 2, tw = t%5 - 2;
        int n2 = td*td + th*th + tw*tw;
        if (t == 62) {
            for (int r = 0; r < 3; r++) {
                float tt = (0.f - 1.25f*(float)r) * 0.8f;
                T.Rc[r] = cexpf_(-tt*tt);
            }
            continue;
        }
        bool active = n2 <= 6;
        bool pos = (td>0) || (td==0 && th>0) || (td==0 && th==0 && tw>0);
        if (!(active && pos)) continue;
        T.op[idx] = (td*96 + th*12 + tw) * 10;
        float norm = csqrtf_((float)n2);
        float comp[3] = {(float)td, (float)th, (float)tw};
        for (int r = 0; r < 3; r++) {
            float tt = (norm - 1.25f*(float)r) * 0.8f;
            float R = cexpf_(-tt*tt);
            T.R[idx][r] = R;
            for (int m = 0; m < 3; m++)
                T.RY[idx][r*3+m] = R * 1.7320508075688772f * comp[m] / norm;
        }
        idx++;
    }
    return T;
}
__device__ constexpr TapTab TT = make_taps();

// ---------------------------------------------------------------- W matrices (fp32 source)
__global__ void build_W(float* __restrict__ W,
    const float* __restrict__ ss1, const float* __restrict__ sv1,
    const float* __restrict__ vs1, const float* __restrict__ vv01, const float* __restrict__ vv11,
    const float* __restrict__ ss2, const float* __restrict__ sv2,
    const float* __restrict__ vs2, const float* __restrict__ vv02, const float* __restrict__ vv12)
{
    int idx = threadIdx.x + blockIdx.x * 256;
    if (idx >= 184320) return;
    int conv = idx / 92160;
    int rem  = idx % 92160;
    int j  = rem / 7680;
    int ci = (rem / 96) % 80;
    int co = rem % 96;
    int r = j >> 2, al = j & 3;
    const float* ss  = conv ? ss2  : ss1;
    const float* sv  = conv ? sv2  : sv1;
    const float* vs  = conv ? vs2  : vs1;
    const float* vv0 = conv ? vv02 : vv01;
    const float* vv1 = conv ? vv12 : vv11;
    float val = 0.f;
    if (ci < 32) {
        if (co < 48) { if (al == 0) val = ss[(r*32 + ci)*48 + co]; }
        else {
            int o = (co - 48) / 3, m = (co - 48) % 3;
            if (al == m + 1) val = sv[(r*32 + ci)*16 + o];
        }
    } else {
        int i = (ci - 32) / 3, a = (ci - 32) % 3;
        if (co < 48) { if (al == a + 1) val = vs[(r*16 + i)*48 + co] * 0.5773502691896258f; }
        else {
            int o = (co - 48) / 3, b = (co - 48) % 3;
            if (al == 0) { if (a == b) val = vv0[(r*16 + i)*16 + o]; }
            else {
                int e = eps3(a, al - 1, b);
                if (e) val = vv1[(r*16 + i)*16 + o] * (float)e * 0.7071067811865476f;
            }
        }
    }
    W[idx] = val;
}

// ---------------------------------------------------------------- W split bf16 hi/lo, chunk-permuted
// Wc[conv][co][k'],  k' = c10*96 + cg*24 + e*12 + j;  ci = c10*8 + cg*2 + e;  k = j*80+ci
__global__ void build_Wc(const float* __restrict__ W,
                         unsigned short* __restrict__ Wh, unsigned short* __restrict__ Wl)
{
    int idx = threadIdx.x + blockIdx.x * 256;    // over 2*96*960
    if (idx >= 184320) return;
    int conv = idx / 92160, rem = idx % 92160;
    int co = rem / 960, kp = rem % 960;
    int c10 = kp / 96, r2 = kp % 96;
    int cg = r2 / 24, r3 = r2 % 24;
    int e = r3 / 12, j = r3 % 12;
    int ci = c10 * 8 + cg * 2 + e;
    int k = j * 80 + ci;
    float w = W[conv * 92160 + k * 96 + co];
    unsigned int u = __float_as_uint(w);
    unsigned int hib = (u + 0x7FFFu + ((u >> 16) & 1u)) & 0xFFFF0000u;  // RNE bf16
    float res = w - __uint_as_float(hib);
    unsigned int v = __float_as_uint(res);
    unsigned int lob = (v + 0x7FFFu + ((v >> 16) & 1u)) >> 16;
    Wh[idx] = (unsigned short)(hib >> 16);
    Wl[idx] = (unsigned short)lob;
}

// ---------------------------------------------------------------- fused conv
// LDS map (floats): [0,5760) halo[576 pos][10]
//                   ushort region at +5760 fl: zc 2 bufs x {hi[64][104], lo[64][104]}
//                   buf b: base b*13312 ush; hi +0, lo +6656.   Total 76288 B.
// epilogue reuses floats [0, 6272) as y[64][98]

__device__ __forceinline__ void halo_slot(int i, int dt, int h0, int w0, int& go, int& lo) {
    int pos = i >> 1, half = i & 1;
    int hd = pos / 96, rm = pos - hd * 96;
    int hh = rm / 12, hw = rm - hh * 12;
    int gd = dt + hd - 2, gh = h0 + hh - 2, gw = w0 + hw - 2;
    go = (gd >= 0 && gd < 32 && gh >= 0 && gh < 32 && gw >= 0 && gw < 32)
       ? (((gd << 5) + gh) * 32 + gw) * 80 + half * 4 : -1;
    lo = pos * 10 + half * 4;
}

__device__ __forceinline__ void stageA(
    const float* __restrict__ smem, unsigned short* __restrict__ zch,
    unsigned short* __restrict__ zcl, int vox, int cg)
{
    int pos = ((vox >> 5) + 2) * 96 + (((vox >> 3) & 3) + 2) * 12 + (vox & 7) + 2;
    const float* xpb = smem + pos * 10 + 2 * cg - 2180;   // bias: max |op| = 2180
    float az[12][2];
    #pragma unroll
    for (int j = 0; j < 12; j++) { az[j][0] = 0.f; az[j][1] = 0.f; }
    {   // center
        float2 xc = *reinterpret_cast<const float2*>(xpb + 2180);
        #pragma unroll
        for (int r = 0; r < 3; r++) {
            float R = TT.Rc[r];
            az[r*4][0] += R * xc.x; az[r*4][1] += R * xc.y;
        }
    }
    #pragma unroll
    for (int p = 0; p < 40; p++) {
        float2 xa = *reinterpret_cast<const float2*>(xpb + (2180 + TT.op[p]));
        float2 xb = *reinterpret_cast<const float2*>(xpb + (2180 - TT.op[p]));
        float s0 = xa.x + xb.x, s1 = xa.y + xb.y;
        float d0 = xa.x - xb.x, d1 = xa.y - xb.y;
        #pragma unroll
        for (int r = 0; r < 3; r++) {
            float R = TT.R[p][r];
            az[r*4][0] += R * s0; az[r*4][1] += R * s1;
            #pragma unroll
            for (int m = 0; m < 3; m++) {
                float RY = TT.RY[p][r*3+m];
                az[r*4 + m + 1][0] += RY * d0;
                az[r*4 + m + 1][1] += RY * d1;
            }
        }
    }
    // split to bf16 hi/lo, pack: k_local = cg*24 + e*12 + j (contiguous 24 ush)
    unsigned int uh[12], ul[12];
    #pragma unroll
    for (int e = 0; e < 2; e++)
        #pragma unroll
        for (int j2 = 0; j2 < 6; j2++) {
            float a0 = az[2*j2][e], a1 = az[2*j2+1][e];
            unsigned int b0 = __float_as_uint(a0), b1 = __float_as_uint(a1);
            float r0 = a0 - __uint_as_float(b0 & 0xFFFF0000u);
            float r1 = a1 - __uint_as_float(b1 & 0xFFFF0000u);
            uh[e*6 + j2] = (b0 >> 16) | ((b1 >> 16) << 16);
            ul[e*6 + j2] = (__float_as_uint(r0) >> 16) | ((__float_as_uint(r1) >> 16) << 16);
        }
    int base = vox * 104 + cg * 24;        // ushort offset, 16B-aligned pieces
    *reinterpret_cast<u32x4*>(zch + base)      = (u32x4){uh[0], uh[1], uh[2],  uh[3]};
    *reinterpret_cast<u32x4*>(zch + base + 8)  = (u32x4){uh[4], uh[5], uh[6],  uh[7]};
    *reinterpret_cast<u32x4*>(zch + base + 16) = (u32x4){uh[8], uh[9], uh[10], uh[11]};
    *reinterpret_cast<u32x4*>(zcl + base)      = (u32x4){ul[0], ul[1], ul[2],  ul[3]};
    *reinterpret_cast<u32x4*>(zcl + base + 8)  = (u32x4){ul[4], ul[5], ul[6],  ul[7]};
    *reinterpret_cast<u32x4*>(zcl + base + 16) = (u32x4){ul[8], ul[9], ul[10], ul[11]};
}

__device__ __forceinline__ void stageB(
    const unsigned short* __restrict__ zch, const unsigned short* __restrict__ zcl,
    const unsigned short* __restrict__ Wh, const unsigned short* __restrict__ Wl,
    int c10, int brow, int lr, int lk, f32x4* acc)
{
    const unsigned short* zh = zch + brow * 104 + lk * 8;
    const unsigned short* zl = zcl + brow * 104 + lk * 8;
    const unsigned short* wb  = Wh + lr * 960 + c10 * 96 + lk * 8;
    const unsigned short* wbl = Wl + lr * 960 + c10 * 96 + lk * 8;
    #pragma unroll
    for (int ks = 0; ks < 3; ks++) {
        bf16x8 ah = *reinterpret_cast<const bf16x8*>(zh + ks * 32);
        bf16x8 al = *reinterpret_cast<const bf16x8*>(zl + ks * 32);
        #pragma unroll
        for (int nt = 0; nt < 6; nt++) {
            bf16x8 bh = *reinterpret_cast<const bf16x8*>(wb  + nt * 15360 + ks * 32);
            bf16x8 bl = *reinterpret_cast<const bf16x8*>(wbl + nt * 15360 + ks * 32);
            acc[nt] = __builtin_amdgcn_mfma_f32_16x16x32_bf16(ah, bh, acc[nt], 0, 0, 0);
            acc[nt] = __builtin_amdgcn_mfma_f32_16x16x32_bf16(al, bh, acc[nt], 0, 0, 0);
            acc[nt] = __builtin_amdgcn_mfma_f32_16x16x32_bf16(ah, bl, acc[nt], 0, 0, 0);
        }
    }
}

__global__ __attribute__((amdgpu_flat_work_group_size(512, 512), amdgpu_waves_per_eu(4)))
void fused_conv(
    const float* __restrict__ xin, const unsigned short* __restrict__ Wh,
    const unsigned short* __restrict__ Wl, float* __restrict__ xout)
{
    __shared__ float smem[19072];                       // 76,288 B -> 2 blocks/CU
    unsigned short* zc = reinterpret_cast<unsigned short*>(smem + 5760);
    int t = threadIdx.x;
    int wv = t >> 6, l = t & 63;
    bool Aw = wv < 4;
    int vox = t & 63, cg = wv & 3;                      // stage-A decode
    int lr = l & 15, lk = l >> 4;                       // MFMA lane decode
    int rowbase = (wv & 3) * 16;                        // stage-B rows
    int brow = rowbase + lr;
    int bid = blockIdx.x;
    int dt = (bid >> 5) << 1;
    int h0 = ((bid >> 2) & 7) << 2;
    int w0 = (bid & 3) << 3;

    // steady-state halo slots (B-threads): 1152 float4 / 256 thr = 5 (guarded)
    int go5[5], lo5[5];
    if (!Aw) {
        #pragma unroll
        for (int q = 0; q < 5; q++) {
            int i = (t - 256) + q * 256;
            if (i < 1152) halo_slot(i, dt, h0, w0, go5[q], lo5[q]);
            else { go5[q] = -2; lo5[q] = 0; }
        }
    }

    // prologue: halo chunk 0 (all threads)
    #pragma unroll
    for (int q = 0; q < 3; q++) {
        int i = t + q * 512;
        if (i < 1152) {
            int go, lo; halo_slot(i, dt, h0, w0, go, lo);
            float4 v = (go >= 0) ? *reinterpret_cast<const float4*>(xin + go)
                                 : make_float4(0.f, 0.f, 0.f, 0.f);
            *reinterpret_cast<float4*>(smem + lo) = v;
        }
    }
    __syncthreads();

    const f32x4 fzero = {0.f, 0.f, 0.f, 0.f};
    f32x4 acc[6];
    #pragma unroll
    for (int nt = 0; nt < 6; nt++) acc[nt] = fzero;

    for (int c = 0; c < 10; c++) {
        float4 pf[5];
        if (!Aw && c < 9) {                              // issue next-chunk halo loads
            #pragma unroll
            for (int q = 0; q < 5; q++)
                if (go5[q] != -2)
                    pf[q] = (go5[q] >= 0)
                          ? *reinterpret_cast<const float4*>(xin + go5[q] + (c + 1) * 8)
                          : make_float4(0.f, 0.f, 0.f, 0.f);
        }
        // P1: A(c) || B(c-1)
        unsigned short* zb = zc + (c & 1) * 13312;
        if (Aw) stageA(smem, zb, zb + 6656, vox, cg);
        else if (c > 0) {
            const unsigned short* rb = zc + ((c - 1) & 1) * 13312;
            stageB(rb, rb + 6656, Wh, Wl, c - 1, brow, lr, lk, acc);
        }
        __syncthreads();
        // P2: write halo chunk c+1
        if (!Aw && c < 9) {
            #pragma unroll
            for (int q = 0; q < 5; q++)
                if (go5[q] != -2) *reinterpret_cast<float4*>(smem + lo5[q]) = pf[q];
        }
        __syncthreads();
    }
    // tail: B(9)
    if (!Aw) {
        const unsigned short* rb = zc + 13312;           // 9&1 = 1
        stageB(rb, rb + 6656, Wh, Wl, 9, brow, lr, lk, acc);
    }
    __syncthreads();

    // epilogue: y -> gate -> store (reuse smem as y[64][98])
    float* y = smem;
    if (!Aw) {
        // C/D layout: col = lane&15, row = (lane>>4)*4 + reg
        #pragma unroll
        for (int nt = 0; nt < 6; nt++)
            #pragma unroll
            for (int r = 0; r < 4; r++)
                y[(rowbase + lk * 4 + r) * 98 + nt * 16 + lr] = acc[nt][r];
    }
    __syncthreads();
    #pragma unroll
    for (int it = 0; it < 10; it++) {
        int idx = t + it * 512;
        int vr = idx / 80, c = idx - vr * 80;
        int gd = dt + (vr >> 5), gh = h0 + ((vr >> 3) & 3), gw = w0 + (vr & 7);
        const float* yr = y + vr * 98;
        float val;
        if (c < 32) val = fmaxf(yr[c], 0.f);
        else {
            int q = c - 32;
            float g = 1.f / (1.f + __expf(-yr[32 + q / 3]));
            val = yr[48 + q] * g;
        }
        xout[(size_t)(((gd << 5) + gh) * 32 + gw) * 80 + c] = val;
    }
}

// ---------------------------------------------------------------- Final head (nontemporal stores)
__global__ __launch_bounds__(256) void final_k(
    const float* __restrict__ x2, const float* __restrict__ wls,
    const float* __restrict__ wlv, const float* __restrict__ wpos,
    float* __restrict__ out)
{
    __shared__ float xv[16 * 81];
    __shared__ float coeff[16 * 161];
    __shared__ float s_wls[512];
    __shared__ float s_wlv[768];
    int t = threadIdx.x;
    int bid = blockIdx.x;
    int cw0 = (bid & 1) * 16;
    int ch  = (bid >> 1) & 31;
    int cd  = bid >> 6;
    float wp = wpos[0];
    {
        int base = ((cd * 32 + ch) * 32 + cw0) * 80;
        #pragma unroll
        for (int i = t; i < 1280; i += 256) {
            int vi = i / 80, c = i % 80;
            xv[vi * 81 + c] = x2[base + i];
        }
        for (int i = t; i < 512; i += 256) s_wls[i] = wls[i];
        for (int i = t; i < 768; i += 256) s_wlv[i] = wlv[i];
    }
    __syncthreads();
    {
        int vi = t >> 4, j = t & 15;
        const float* xp = xv + vi * 81;
        float* cf = coeff + vi * 161;
        #pragma unroll
        for (int l = 0; l < 10; l++) {
            int q = l * 16 + j;
            float sum = 0.f;
            if (q < 96) {
                int o = q / 3, m = q % 3;
                #pragma unroll
                for (int c = 0; c < 16; c++) sum += xp[32 + c * 3 + m] * s_wls[c * 32 + o];
            } else if (q < 112) {
                int o = q - 96;
                #pragma unroll
                for (int c = 0; c < 32; c++) sum += xp[c] * s_wlv[c * 16 + o];
            } else {
                int q2 = q - 112; int o = q2 / 3, m = q2 % 3;
                #pragma unroll
                for (int c = 0; c < 16; c++) sum += xp[32 + c * 3 + m] * s_wlv[(32 + c) * 16 + o];
            }
            cf[q] = sum;
        }
    }
    __syncthreads();
    const float scale = 0.14433756729740643f;
    #pragma unroll
    for (int f01 = 0; f01 < 4; f01++) {
        int fd = 2 * cd + (f01 >> 1), fh = 2 * ch + (f01 & 1);
        float p0 = wp * (float)(cd + (f01 >> 1) - 16);
        float p1 = wp * (float)(ch + (f01 & 1) - 16);
        size_t obase = (size_t)((fd * 64 + fh) * 64 + cw0 * 2) * 80;
        #pragma unroll
        for (int it = 0; it < 3; it++) {
            int idx4 = it * 256 + t;
            if (idx4 < 640) {
                int base = idx4 * 4;
                int fwl = base / 80, c0 = base - fwl * 80;
                int vi = fwl >> 1;
                float p2 = wp * (float)(cw0 + vi + (fwl & 1) - 16);
                const float* cf = coeff + vi * 161;
                float vv[4];
                if (c0 < 32) {
                    #pragma unroll
                    for (int e = 0; e < 4; e++) {
                        int c = c0 + e;
                        vv[e] = cf[c * 3] * p0 + cf[c * 3 + 1] * p1 + cf[c * 3 + 2] * p2;
                    }
                } else {
                    #pragma unroll
                    for (int e = 0; e < 4; e++) {
                        int q = c0 - 32 + e, o = q / 3, m = q - o * 3;
                        float A = cf[96 + o];
                        const float* w2 = cf + 112 + o * 3;
                        float pm, crm;
                        if (m == 0)      { pm = p0; crm = w2[1] * p2 - w2[2] * p1; }
                        else if (m == 1) { pm = p1; crm = w2[2] * p0 - w2[0] * p2; }
                        else             { pm = p2; crm = w2[0] * p1 - w2[1] * p0; }
                        vv[e] = A * pm + crm * 0.7071067811865476f;
                    }
                }
                f32x4 o4 = {vv[0]*scale, vv[1]*scale, vv[2]*scale, vv[3]*scale};
                __builtin_nontemporal_store(o4, reinterpret_cast<f32x4*>(out + obase + base));
            }
        }
    }
}

// ----------------------------------------------------------------
extern "C" void kernel_launch(void* const* d_in, const int* in_sizes, int n_in,
                              void* d_out, int out_size, void* d_ws, size_t ws_size,
                              hipStream_t stream)
{
    const float* x    = (const float*)d_in[0];
    const float* wpos = (const float*)d_in[11];
    const float* wls  = (const float*)d_in[12];
    const float* wlv  = (const float*)d_in[13];
    float* out = (float*)d_out;
    float* ws  = (float*)d_ws;

    float* W   = ws + 1024;                 // 184320 fp32
    unsigned short* Wh = (unsigned short*)(ws + 1024 + 184320);   // 184320 ushorts
    unsigned short* Wl = Wh + 184320;                              // 184320 ushorts
    float* x1  = ws + 1024 + 184320 + 184320;
    float* x2  = x1 + 2621440;

    build_W<<<720, 256, 0, stream>>>(W,
        (const float*)d_in[1], (const float*)d_in[2], (const float*)d_in[3],
        (const float*)d_in[4], (const float*)d_in[5],
        (const float*)d_in[6], (const float*)d_in[7], (const float*)d_in[8],
        (const float*)d_in[9], (const float*)d_in[10]);
    build_Wc<<<720, 256, 0, stream>>>(W, Wh, Wl);

    fused_conv<<<512, 512, 0, stream>>>(x,  Wh,         Wl,         x1);
    fused_conv<<<512, 512, 0, stream>>>(x1, Wh + 92160, Wl + 92160, x2);
    final_k<<<2048, 256, 0, stream>>>(x2, wls, wlv, wpos, out);
}

// Round 10
// 616.293 us; speedup vs baseline: 1.0015x; 1.0015x over previous
//
#include <hip/hip_runtime.h>
#include <math.h>

// x: [1,32,32,32,80] fp32 (80 = 32 scalars + 16 vec*3)
// conv: low-rank kernel basis 12 = 3 radial * {1, Yd, Yh, Yw}
// FUSED conv, producer/consumer: 512-thr blocks (8 waves), 64-voxel tile (2,4,8),
//   2 blocks/CU (LDS 76.3 KB).  10 chunks of 8 ci.  Fixed roles:
//   waves 0-3 = stage A (tap-pair VALU -> zc[c&1]);  waves 4-7 = stage B
//   (split-bf16 MFMA on zc[(c-1)&1]) + halo prefetch/write.  zc double-buffered.
//   waves_per_eu(4,4): exact 4 waves/EU -> 128-VGPR budget (round 9 spilled at 64).
// out: [1,64,64,64,80] fp32

typedef __attribute__((ext_vector_type(8))) short bf16x8;
typedef __attribute__((ext_vector_type(4))) float f32x4;
typedef __attribute__((ext_vector_type(4))) unsigned int u32x4;

__device__ __forceinline__ int eps3(int a, int m, int b) {
    if (a == b || a == m || m == b) return 0;
    return ((a==0&&m==1&&b==2)||(a==1&&m==2&&b==0)||(a==2&&m==0&&b==1)) ? 1 : -1;
}

// ---------------------------------------------------------------- constexpr tap table
// halo layout: pos = hd*96 + hh*12 + hw  (6x8x12), row stride 10 floats (8 ci + 2 pad)
struct TapTab {
    int   op[40];        // float-offset, positive rep
    float R[40][3];
    float RY[40][9];
    float Rc[3];
};
constexpr float cexpf_(float x) {
    float y = x * (1.f/16.f);
    float s = 1.f + y*(1.f + y*(0.5f + y*((1.f/6.f) + y*((1.f/24.f) + y*(1.f/120.f)))));
    s *= s; s *= s; s *= s; s *= s;
    return s;
}
constexpr float csqrtf_(float x) {
    float g = x > 1.f ? x : 1.f;
    for (int i = 0; i < 40; i++) g = 0.5f*(g + x/g);
    return g;
}
constexpr TapTab make_taps() {
    TapTab T{};
    int idx = 0;
    for (int t = 0; t < 125; t++) {
        int td = t/25 - 2, th = (t/5)%5 - 2, tw = t%5 - 2;
        int n2 = td*td + th*th + tw*tw;
        if (t == 62) {
            for (int r = 0; r < 3; r++) {
                float tt = (0.f - 1.25f*(float)r) * 0.8f;
                T.Rc[r] = cexpf_(-tt*tt);
            }
            continue;
        }
        bool active = n2 <= 6;
        bool pos = (td>0) || (td==0 && th>0) || (td==0 && th==0 && tw>0);
        if (!(active && pos)) continue;
        T.op[idx] = (td*96 + th*12 + tw) * 10;
        float norm = csqrtf_((float)n2);
        float comp[3] = {(float)td, (float)th, (float)tw};
        for (int r = 0; r < 3; r++) {
            float tt = (norm - 1.25f*(float)r) * 0.8f;
            float R = cexpf_(-tt*tt);
            T.R[idx][r] = R;
            for (int m = 0; m < 3; m++)
                T.RY[idx][r*3+m] = R * 1.7320508075688772f * comp[m] / norm;
        }
        idx++;
    }
    return T;
}
__device__ constexpr TapTab TT = make_taps();

// ---------------------------------------------------------------- W matrices (fp32 source)
__global__ void build_W(float* __restrict__ W,
    const float* __restrict__ ss1, const float* __restrict__ sv1,
    const float* __restrict__ vs1, const float* __restrict__ vv01, const float* __restrict__ vv11,
    const float* __restrict__ ss2, const float* __restrict__ sv2,
    const float* __restrict__ vs2, const float* __restrict__ vv02, const float* __restrict__ vv12)
{
    int idx = threadIdx.x + blockIdx.x * 256;
    if (idx >= 184320) return;
    int conv = idx / 92160;
    int rem  = idx % 92160;
    int j  = rem / 7680;
    int ci = (rem / 96) % 80;
    int co = rem % 96;
    int r = j >> 2, al = j & 3;
    const float* ss  = conv ? ss2  : ss1;
    const float* sv  = conv ? sv2  : sv1;
    const float* vs  = conv ? vs2  : vs1;
    const float* vv0 = conv ? vv02 : vv01;
    const float* vv1 = conv ? vv12 : vv11;
    float val = 0.f;
    if (ci < 32) {
        if (co < 48) { if (al == 0) val = ss[(r*32 + ci)*48 + co]; }
        else {
            int o = (co - 48) / 3, m = (co - 48) % 3;
            if (al == m + 1) val = sv[(r*32 + ci)*16 + o];
        }
    } else {
        int i = (ci - 32) / 3, a = (ci - 32) % 3;
        if (co < 48) { if (al == a + 1) val = vs[(r*16 + i)*48 + co] * 0.5773502691896258f; }
        else {
            int o = (co - 48) / 3, b = (co - 48) % 3;
            if (al == 0) { if (a == b) val = vv0[(r*16 + i)*16 + o]; }
            else {
                int e = eps3(a, al - 1, b);
                if (e) val = vv1[(r*16 + i)*16 + o] * (float)e * 0.7071067811865476f;
            }
        }
    }
    W[idx] = val;
}

// ---------------------------------------------------------------- W split bf16 hi/lo, chunk-permuted
// Wc[conv][co][k'],  k' = c10*96 + cg*24 + e*12 + j;  ci = c10*8 + cg*2 + e;  k = j*80+ci
__global__ void build_Wc(const float* __restrict__ W,
                         unsigned short* __restrict__ Wh, unsigned short* __restrict__ Wl)
{
    int idx = threadIdx.x + blockIdx.x * 256;    // over 2*96*960
    if (idx >= 184320) return;
    int conv = idx / 92160, rem = idx % 92160;
    int co = rem / 960, kp = rem % 960;
    int c10 = kp / 96, r2 = kp % 96;
    int cg = r2 / 24, r3 = r2 % 24;
    int e = r3 / 12, j = r3 % 12;
    int ci = c10 * 8 + cg * 2 + e;
    int k = j * 80 + ci;
    float w = W[conv * 92160 + k * 96 + co];
    unsigned int u = __float_as_uint(w);
    unsigned int hib = (u + 0x7FFFu + ((u >> 16) & 1u)) & 0xFFFF0000u;  // RNE bf16
    float res = w - __uint_as_float(hib);
    unsigned int v = __float_as_uint(res);
    unsigned int lob = (v + 0x7FFFu + ((v >> 16) & 1u)) >> 16;
    Wh[idx] = (unsigned short)(hib >> 16);
    Wl[idx] = (unsigned short)lob;
}

// ---------------------------------------------------------------- fused conv
// LDS map (floats): [0,5760) halo[576 pos][10]
//                   ushort region at +5760 fl: zc 2 bufs x {hi[64][104], lo[64][104]}
//                   buf b: base b*13312 ush; hi +0, lo +6656.   Total 76288 B.
// epilogue reuses floats [0, 6272) as y[64][98]

__device__ __forceinline__ void halo_slot(int i, int dt, int h0, int w0, int& go, int& lo) {
    int pos = i >> 1, half = i & 1;
    int hd = pos / 96, rm = pos - hd * 96;
    int hh = rm / 12, hw = rm - hh * 12;
    int gd = dt + hd - 2, gh = h0 + hh - 2, gw = w0 + hw - 2;
    go = (gd >= 0 && gd < 32 && gh >= 0 && gh < 32 && gw >= 0 && gw < 32)
       ? (((gd << 5) + gh) * 32 + gw) * 80 + half * 4 : -1;
    lo = pos * 10 + half * 4;
}

__device__ __forceinline__ void stageA(
    const float* __restrict__ smem, unsigned short* __restrict__ zch,
    unsigned short* __restrict__ zcl, int vox, int cg)
{
    int pos = ((vox >> 5) + 2) * 96 + (((vox >> 3) & 3) + 2) * 12 + (vox & 7) + 2;
    const float* xpb = smem + pos * 10 + 2 * cg - 2180;   // bias: max |op| = 2180
    float az[12][2];
    #pragma unroll
    for (int j = 0; j < 12; j++) { az[j][0] = 0.f; az[j][1] = 0.f; }
    {   // center
        float2 xc = *reinterpret_cast<const float2*>(xpb + 2180);
        #pragma unroll
        for (int r = 0; r < 3; r++) {
            float R = TT.Rc[r];
            az[r*4][0] += R * xc.x; az[r*4][1] += R * xc.y;
        }
    }
    #pragma unroll
    for (int p = 0; p < 40; p++) {
        float2 xa = *reinterpret_cast<const float2*>(xpb + (2180 + TT.op[p]));
        float2 xb = *reinterpret_cast<const float2*>(xpb + (2180 - TT.op[p]));
        float s0 = xa.x + xb.x, s1 = xa.y + xb.y;
        float d0 = xa.x - xb.x, d1 = xa.y - xb.y;
        #pragma unroll
        for (int r = 0; r < 3; r++) {
            float R = TT.R[p][r];
            az[r*4][0] += R * s0; az[r*4][1] += R * s1;
            #pragma unroll
            for (int m = 0; m < 3; m++) {
                float RY = TT.RY[p][r*3+m];
                az[r*4 + m + 1][0] += RY * d0;
                az[r*4 + m + 1][1] += RY * d1;
            }
        }
    }
    // split to bf16 hi/lo, pack: k_local = cg*24 + e*12 + j (contiguous 24 ush)
    unsigned int uh[12], ul[12];
    #pragma unroll
    for (int e = 0; e < 2; e++)
        #pragma unroll
        for (int j2 = 0; j2 < 6; j2++) {
            float a0 = az[2*j2][e], a1 = az[2*j2+1][e];
            unsigned int b0 = __float_as_uint(a0), b1 = __float_as_uint(a1);
            float r0 = a0 - __uint_as_float(b0 & 0xFFFF0000u);
            float r1 = a1 - __uint_as_float(b1 & 0xFFFF0000u);
            uh[e*6 + j2] = (b0 >> 16) | ((b1 >> 16) << 16);
            ul[e*6 + j2] = (__float_as_uint(r0) >> 16) | ((__float_as_uint(r1) >> 16) << 16);
        }
    int base = vox * 104 + cg * 24;        // ushort offset, 16B-aligned pieces
    *reinterpret_cast<u32x4*>(zch + base)      = (u32x4){uh[0], uh[1], uh[2],  uh[3]};
    *reinterpret_cast<u32x4*>(zch + base + 8)  = (u32x4){uh[4], uh[5], uh[6],  uh[7]};
    *reinterpret_cast<u32x4*>(zch + base + 16) = (u32x4){uh[8], uh[9], uh[10], uh[11]};
    *reinterpret_cast<u32x4*>(zcl + base)      = (u32x4){ul[0], ul[1], ul[2],  ul[3]};
    *reinterpret_cast<u32x4*>(zcl + base + 8)  = (u32x4){ul[4], ul[5], ul[6],  ul[7]};
    *reinterpret_cast<u32x4*>(zcl + base + 16) = (u32x4){ul[8], ul[9], ul[10], ul[11]};
}

__device__ __forceinline__ void stageB(
    const unsigned short* __restrict__ zch, const unsigned short* __restrict__ zcl,
    const unsigned short* __restrict__ Wh, const unsigned short* __restrict__ Wl,
    int c10, int brow, int lr, int lk, f32x4* acc)
{
    const unsigned short* zh = zch + brow * 104 + lk * 8;
    const unsigned short* zl = zcl + brow * 104 + lk * 8;
    const unsigned short* wb  = Wh + lr * 960 + c10 * 96 + lk * 8;
    const unsigned short* wbl = Wl + lr * 960 + c10 * 96 + lk * 8;
    #pragma unroll
    for (int ks = 0; ks < 3; ks++) {
        bf16x8 ah = *reinterpret_cast<const bf16x8*>(zh + ks * 32);
        bf16x8 al = *reinterpret_cast<const bf16x8*>(zl + ks * 32);
        #pragma unroll
        for (int nt = 0; nt < 6; nt++) {
            bf16x8 bh = *reinterpret_cast<const bf16x8*>(wb  + nt * 15360 + ks * 32);
            bf16x8 bl = *reinterpret_cast<const bf16x8*>(wbl + nt * 15360 + ks * 32);
            acc[nt] = __builtin_amdgcn_mfma_f32_16x16x32_bf16(ah, bh, acc[nt], 0, 0, 0);
            acc[nt] = __builtin_amdgcn_mfma_f32_16x16x32_bf16(al, bh, acc[nt], 0, 0, 0);
            acc[nt] = __builtin_amdgcn_mfma_f32_16x16x32_bf16(ah, bl, acc[nt], 0, 0, 0);
        }
    }
}

__global__ __attribute__((amdgpu_flat_work_group_size(512, 512), amdgpu_waves_per_eu(4, 4)))
void fused_conv(
    const float* __restrict__ xin, const unsigned short* __restrict__ Wh,
    const unsigned short* __restrict__ Wl, float* __restrict__ xout)
{
    __shared__ float smem[19072];                       // 76,288 B -> 2 blocks/CU
    unsigned short* zc = reinterpret_cast<unsigned short*>(smem + 5760);
    int t = threadIdx.x;
    int wv = t >> 6, l = t & 63;
    bool Aw = wv < 4;
    int vox = t & 63, cg = wv & 3;                      // stage-A decode
    int lr = l & 15, lk = l >> 4;                       // MFMA lane decode
    int rowbase = (wv & 3) * 16;                        // stage-B rows
    int brow = rowbase + lr;
    int bid = blockIdx.x;
    int dt = (bid >> 5) << 1;
    int h0 = ((bid >> 2) & 7) << 2;
    int w0 = (bid & 3) << 3;

    // steady-state halo slots (B-threads): 1152 float4 / 256 thr = 5 (guarded)
    int go5[5], lo5[5];
    if (!Aw) {
        #pragma unroll
        for (int q = 0; q < 5; q++) {
            int i = (t - 256) + q * 256;
            if (i < 1152) halo_slot(i, dt, h0, w0, go5[q], lo5[q]);
            else { go5[q] = -2; lo5[q] = 0; }
        }
    }

    // prologue: halo chunk 0 (all threads)
    #pragma unroll
    for (int q = 0; q < 3; q++) {
        int i = t + q * 512;
        if (i < 1152) {
            int go, lo; halo_slot(i, dt, h0, w0, go, lo);
            float4 v = (go >= 0) ? *reinterpret_cast<const float4*>(xin + go)
                                 : make_float4(0.f, 0.f, 0.f, 0.f);
            *reinterpret_cast<float4*>(smem + lo) = v;
        }
    }
    __syncthreads();

    const f32x4 fzero = {0.f, 0.f, 0.f, 0.f};
    f32x4 acc[6];
    #pragma unroll
    for (int nt = 0; nt < 6; nt++) acc[nt] = fzero;

    for (int c = 0; c < 10; c++) {
        float4 pf[5];
        if (!Aw && c < 9) {                              // issue next-chunk halo loads
            #pragma unroll
            for (int q = 0; q < 5; q++)
                if (go5[q] != -2)
                    pf[q] = (go5[q] >= 0)
                          ? *reinterpret_cast<const float4*>(xin + go5[q] + (c + 1) * 8)
                          : make_float4(0.f, 0.f, 0.f, 0.f);
        }
        // P1: A(c) || B(c-1)
        unsigned short* zb = zc + (c & 1) * 13312;
        if (Aw) stageA(smem, zb, zb + 6656, vox, cg);
        else if (c > 0) {
            const unsigned short* rb = zc + ((c - 1) & 1) * 13312;
            stageB(rb, rb + 6656, Wh, Wl, c - 1, brow, lr, lk, acc);
        }
        __syncthreads();
        // P2: write halo chunk c+1
        if (!Aw && c < 9) {
            #pragma unroll
            for (int q = 0; q < 5; q++)
                if (go5[q] != -2) *reinterpret_cast<float4*>(smem + lo5[q]) = pf[q];
        }
        __syncthreads();
    }
    // tail: B(9)
    if (!Aw) {
        const unsigned short* rb = zc + 13312;           // 9&1 = 1
        stageB(rb, rb + 6656, Wh, Wl, 9, brow, lr, lk, acc);
    }
    __syncthreads();

    // epilogue: y -> gate -> store (reuse smem as y[64][98])
    float* y = smem;
    if (!Aw) {
        // C/D layout: col = lane&15, row = (lane>>4)*4 + reg
        #pragma unroll
        for (int nt = 0; nt < 6; nt++)
            #pragma unroll
            for (int r = 0; r < 4; r++)
                y[(rowbase + lk * 4 + r) * 98 + nt * 16 + lr] = acc[nt][r];
    }
    __syncthreads();
    #pragma unroll
    for (int it = 0; it < 10; it++) {
        int idx = t + it * 512;
        int vr = idx / 80, c = idx - vr * 80;
        int gd = dt + (vr >> 5), gh = h0 + ((vr >> 3) & 3), gw = w0 + (vr & 7);
        const float* yr = y + vr * 98;
        float val;
        if (c < 32) val = fmaxf(yr[c], 0.f);
        else {
            int q = c - 32;
            float g = 1.f / (1.f + __expf(-yr[32 + q / 3]));
            val = yr[48 + q] * g;
        }
        xout[(size_t)(((gd << 5) + gh) * 32 + gw) * 80 + c] = val;
    }
}

// ---------------------------------------------------------------- Final head (nontemporal stores)
__global__ __launch_bounds__(256) void final_k(
    const float* __restrict__ x2, const float* __restrict__ wls,
    const float* __restrict__ wlv, const float* __restrict__ wpos,
    float* __restrict__ out)
{
    __shared__ float xv[16 * 81];
    __shared__ float coeff[16 * 161];
    __shared__ float s_wls[512];
    __shared__ float s_wlv[768];
    int t = threadIdx.x;
    int bid = blockIdx.x;
    int cw0 = (bid & 1) * 16;
    int ch  = (bid >> 1) & 31;
    int cd  = bid >> 6;
    float wp = wpos[0];
    {
        int base = ((cd * 32 + ch) * 32 + cw0) * 80;
        #pragma unroll
        for (int i = t; i < 1280; i += 256) {
            int vi = i / 80, c = i % 80;
            xv[vi * 81 + c] = x2[base + i];
        }
        for (int i = t; i < 512; i += 256) s_wls[i] = wls[i];
        for (int i = t; i < 768; i += 256) s_wlv[i] = wlv[i];
    }
    __syncthreads();
    {
        int vi = t >> 4, j = t & 15;
        const float* xp = xv + vi * 81;
        float* cf = coeff + vi * 161;
        #pragma unroll
        for (int l = 0; l < 10; l++) {
            int q = l * 16 + j;
            float sum = 0.f;
            if (q < 96) {
                int o = q / 3, m = q % 3;
                #pragma unroll
                for (int c = 0; c < 16; c++) sum += xp[32 + c * 3 + m] * s_wls[c * 32 + o];
            } else if (q < 112) {
                int o = q - 96;
                #pragma unroll
                for (int c = 0; c < 32; c++) sum += xp[c] * s_wlv[c * 16 + o];
            } else {
                int q2 = q - 112; int o = q2 / 3, m = q2 % 3;
                #pragma unroll
                for (int c = 0; c < 16; c++) sum += xp[32 + c * 3 + m] * s_wlv[(32 + c) * 16 + o];
            }
            cf[q] = sum;
        }
    }
    __syncthreads();
    const float scale = 0.14433756729740643f;
    #pragma unroll
    for (int f01 = 0; f01 < 4; f01++) {
        int fd = 2 * cd + (f01 >> 1), fh = 2 * ch + (f01 & 1);
        float p0 = wp * (float)(cd + (f01 >> 1) - 16);
        float p1 = wp * (float)(ch + (f01 & 1) - 16);
        size_t obase = (size_t)((fd * 64 + fh) * 64 + cw0 * 2) * 80;
        #pragma unroll
        for (int it = 0; it < 3; it++) {
            int idx4 = it * 256 + t;
            if (idx4 < 640) {
                int base = idx4 * 4;
                int fwl = base / 80, c0 = base - fwl * 80;
                int vi = fwl >> 1;
                float p2 = wp * (float)(cw0 + vi + (fwl & 1) - 16);
                const float* cf = coeff + vi * 161;
                float vv[4];
                if (c0 < 32) {
                    #pragma unroll
                    for (int e = 0; e < 4; e++) {
                        int c = c0 + e;
                        vv[e] = cf[c * 3] * p0 + cf[c * 3 + 1] * p1 + cf[c * 3 + 2] * p2;
                    }
                } else {
                    #pragma unroll
                    for (int e = 0; e < 4; e++) {
                        int q = c0 - 32 + e, o = q / 3, m = q - o * 3;
                        float A = cf[96 + o];
                        const float* w2 = cf + 112 + o * 3;
                        float pm, crm;
                        if (m == 0)      { pm = p0; crm = w2[1] * p2 - w2[2] * p1; }
                        else if (m == 1) { pm = p1; crm = w2[2] * p0 - w2[0] * p2; }
                        else             { pm = p2; crm = w2[0] * p1 - w2[1] * p0; }
                        vv[e] = A * pm + crm * 0.7071067811865476f;
                    }
                }
                f32x4 o4 = {vv[0]*scale, vv[1]*scale, vv[2]*scale, vv[3]*scale};
                __builtin_nontemporal_store(o4, reinterpret_cast<f32x4*>(out + obase + base));
            }
        }
    }
}

// ----------------------------------------------------------------
extern "C" void kernel_launch(void* const* d_in, const int* in_sizes, int n_in,
                              void* d_out, int out_size, void* d_ws, size_t ws_size,
                              hipStream_t stream)
{
    const float* x    = (const float*)d_in[0];
    const float* wpos = (const float*)d_in[11];
    const float* wls  = (const float*)d_in[12];
    const float* wlv  = (const float*)d_in[13];
    float* out = (float*)d_out;
    float* ws  = (float*)d_ws;

    float* W   = ws + 1024;                 // 184320 fp32
    unsigned short* Wh = (unsigned short*)(ws + 1024 + 184320);   // 184320 ushorts
    unsigned short* Wl = Wh + 184320;                              // 184320 ushorts
    float* x1  = ws + 1024 + 184320 + 184320;
    float* x2  = x1 + 2621440;

    build_W<<<720, 256, 0, stream>>>(W,
        (const float*)d_in[1], (const float*)d_in[2], (const float*)d_in[3],
        (const float*)d_in[4], (const float*)d_in[5],
        (const float*)d_in[6], (const float*)d_in[7], (const float*)d_in[8],
        (const float*)d_in[9], (const float*)d_in[10]);
    build_Wc<<<720, 256, 0, stream>>>(W, Wh, Wl);

    fused_conv<<<512, 512, 0, stream>>>(x,  Wh,         Wl,         x1);
    fused_conv<<<512, 512, 0, stream>>>(x1, Wh + 92160, Wl + 92160, x2);
    final_k<<<2048, 256, 0, stream>>>(x2, wls, wlv, wpos, out);
}

// Round 11
// 609.984 us; speedup vs baseline: 1.0118x; 1.0103x over previous
//
#include <hip/hip_runtime.h>
#include <math.h>

// x: [1,32,32,32,80] fp32 (80 = 32 scalars + 16 vec*3)
// conv: low-rank kernel basis 12 = 3 radial * {1, Yd, Yh, Yw}
// FUSED conv, producer/consumer: 512-thr blocks (8 waves), 64-voxel tile (2,4,8),
//   2 blocks/CU (LDS 76.3 KB).  10 chunks of 8 ci.  Fixed roles:
//   waves 0-3 = stage A (tap-pair VALU -> zc[c&1]);  waves 4-7 = stage B
//   (split-bf16 MFMA on zc[(c-1)&1], NAMED accumulators inlined at one site)
//   + direct halo load->LDS in P2 (no register prefetch: round 9/10 spilled).
// out: [1,64,64,64,80] fp32

typedef __attribute__((ext_vector_type(8))) short bf16x8;
typedef __attribute__((ext_vector_type(4))) float f32x4;
typedef __attribute__((ext_vector_type(4))) unsigned int u32x4;

__device__ __forceinline__ int eps3(int a, int m, int b) {
    if (a == b || a == m || m == b) return 0;
    return ((a==0&&m==1&&b==2)||(a==1&&m==2&&b==0)||(a==2&&m==0&&b==1)) ? 1 : -1;
}

// ---------------------------------------------------------------- constexpr tap table
// halo layout: pos = hd*96 + hh*12 + hw  (6x8x12), row stride 10 floats (8 ci + 2 pad)
struct TapTab {
    int   op[40];        // float-offset, positive rep
    float R[40][3];
    float RY[40][9];
    float Rc[3];
};
constexpr float cexpf_(float x) {
    float y = x * (1.f/16.f);
    float s = 1.f + y*(1.f + y*(0.5f + y*((1.f/6.f) + y*((1.f/24.f) + y*(1.f/120.f)))));
    s *= s; s *= s; s *= s; s *= s;
    return s;
}
constexpr float csqrtf_(float x) {
    float g = x > 1.f ? x : 1.f;
    for (int i = 0; i < 40; i++) g = 0.5f*(g + x/g);
    return g;
}
constexpr TapTab make_taps() {
    TapTab T{};
    int idx = 0;
    for (int t = 0; t < 125; t++) {
        int td = t/25 - 2, th = (t/5)%5 - 2, tw = t%5 - 2;
        int n2 = td*td + th*th + tw*tw;
        if (t == 62) {
            for (int r = 0; r < 3; r++) {
                float tt = (0.f - 1.25f*(float)r) * 0.8f;
                T.Rc[r] = cexpf_(-tt*tt);
            }
            continue;
        }
        bool active = n2 <= 6;
        bool pos = (td>0) || (td==0 && th>0) || (td==0 && th==0 && tw>0);
        if (!(active && pos)) continue;
        T.op[idx] = (td*96 + th*12 + tw) * 10;
        float norm = csqrtf_((float)n2);
        float comp[3] = {(float)td, (float)th, (float)tw};
        for (int r = 0; r < 3; r++) {
            float tt = (norm - 1.25f*(float)r) * 0.8f;
            float R = cexpf_(-tt*tt);
            T.R[idx][r] = R;
            for (int m = 0; m < 3; m++)
                T.RY[idx][r*3+m] = R * 1.7320508075688772f * comp[m] / norm;
        }
        idx++;
    }
    return T;
}
__device__ constexpr TapTab TT = make_taps();

// ---------------------------------------------------------------- W matrices (fp32 source)
__global__ void build_W(float* __restrict__ W,
    const float* __restrict__ ss1, const float* __restrict__ sv1,
    const float* __restrict__ vs1, const float* __restrict__ vv01, const float* __restrict__ vv11,
    const float* __restrict__ ss2, const float* __restrict__ sv2,
    const float* __restrict__ vs2, const float* __restrict__ vv02, const float* __restrict__ vv12)
{
    int idx = threadIdx.x + blockIdx.x * 256;
    if (idx >= 184320) return;
    int conv = idx / 92160;
    int rem  = idx % 92160;
    int j  = rem / 7680;
    int ci = (rem / 96) % 80;
    int co = rem % 96;
    int r = j >> 2, al = j & 3;
    const float* ss  = conv ? ss2  : ss1;
    const float* sv  = conv ? sv2  : sv1;
    const float* vs  = conv ? vs2  : vs1;
    const float* vv0 = conv ? vv02 : vv01;
    const float* vv1 = conv ? vv12 : vv11;
    float val = 0.f;
    if (ci < 32) {
        if (co < 48) { if (al == 0) val = ss[(r*32 + ci)*48 + co]; }
        else {
            int o = (co - 48) / 3, m = (co - 48) % 3;
            if (al == m + 1) val = sv[(r*32 + ci)*16 + o];
        }
    } else {
        int i = (ci - 32) / 3, a = (ci - 32) % 3;
        if (co < 48) { if (al == a + 1) val = vs[(r*16 + i)*48 + co] * 0.5773502691896258f; }
        else {
            int o = (co - 48) / 3, b = (co - 48) % 3;
            if (al == 0) { if (a == b) val = vv0[(r*16 + i)*16 + o]; }
            else {
                int e = eps3(a, al - 1, b);
                if (e) val = vv1[(r*16 + i)*16 + o] * (float)e * 0.7071067811865476f;
            }
        }
    }
    W[idx] = val;
}

// ---------------------------------------------------------------- W split bf16 hi/lo, chunk-permuted
// Wc[conv][co][k'],  k' = c10*96 + cg*24 + e*12 + j;  ci = c10*8 + cg*2 + e;  k = j*80+ci
__global__ void build_Wc(const float* __restrict__ W,
                         unsigned short* __restrict__ Wh, unsigned short* __restrict__ Wl)
{
    int idx = threadIdx.x + blockIdx.x * 256;    // over 2*96*960
    if (idx >= 184320) return;
    int conv = idx / 92160, rem = idx % 92160;
    int co = rem / 960, kp = rem % 960;
    int c10 = kp / 96, r2 = kp % 96;
    int cg = r2 / 24, r3 = r2 % 24;
    int e = r3 / 12, j = r3 % 12;
    int ci = c10 * 8 + cg * 2 + e;
    int k = j * 80 + ci;
    float w = W[conv * 92160 + k * 96 + co];
    unsigned int u = __float_as_uint(w);
    unsigned int hib = (u + 0x7FFFu + ((u >> 16) & 1u)) & 0xFFFF0000u;  // RNE bf16
    float res = w - __uint_as_float(hib);
    unsigned int v = __float_as_uint(res);
    unsigned int lob = (v + 0x7FFFu + ((v >> 16) & 1u)) >> 16;
    Wh[idx] = (unsigned short)(hib >> 16);
    Wl[idx] = (unsigned short)lob;
}

// ---------------------------------------------------------------- fused conv
// LDS map (floats): [0,5760) halo[576 pos][10]
//                   ushort region at +5760 fl: zc 2 bufs x {hi[64][104], lo[64][104]}
//                   buf b: base b*13312 ush; hi +0, lo +6656.   Total 76288 B.
// epilogue reuses floats [0, 6272) as y[64][98]

__device__ __forceinline__ void halo_slot(int i, int dt, int h0, int w0, int& go, int& lo) {
    int pos = i >> 1, half = i & 1;
    int hd = pos / 96, rm = pos - hd * 96;
    int hh = rm / 12, hw = rm - hh * 12;
    int gd = dt + hd - 2, gh = h0 + hh - 2, gw = w0 + hw - 2;
    go = (gd >= 0 && gd < 32 && gh >= 0 && gh < 32 && gw >= 0 && gw < 32)
       ? (((gd << 5) + gh) * 32 + gw) * 80 + half * 4 : -1;
    lo = pos * 10 + half * 4;
}

__device__ __forceinline__ void stageA(
    const float* __restrict__ smem, unsigned short* __restrict__ zch,
    unsigned short* __restrict__ zcl, int vox, int cg)
{
    int pos = ((vox >> 5) + 2) * 96 + (((vox >> 3) & 3) + 2) * 12 + (vox & 7) + 2;
    const float* xpb = smem + pos * 10 + 2 * cg - 2180;   // bias: max |op| = 2180
    float az[12][2];
    #pragma unroll
    for (int j = 0; j < 12; j++) { az[j][0] = 0.f; az[j][1] = 0.f; }
    {   // center
        float2 xc = *reinterpret_cast<const float2*>(xpb + 2180);
        #pragma unroll
        for (int r = 0; r < 3; r++) {
            float R = TT.Rc[r];
            az[r*4][0] += R * xc.x; az[r*4][1] += R * xc.y;
        }
    }
    #pragma unroll
    for (int p = 0; p < 40; p++) {
        float2 xa = *reinterpret_cast<const float2*>(xpb + (2180 + TT.op[p]));
        float2 xb = *reinterpret_cast<const float2*>(xpb + (2180 - TT.op[p]));
        float s0 = xa.x + xb.x, s1 = xa.y + xb.y;
        float d0 = xa.x - xb.x, d1 = xa.y - xb.y;
        #pragma unroll
        for (int r = 0; r < 3; r++) {
            float R = TT.R[p][r];
            az[r*4][0] += R * s0; az[r*4][1] += R * s1;
            #pragma unroll
            for (int m = 0; m < 3; m++) {
                float RY = TT.RY[p][r*3+m];
                az[r*4 + m + 1][0] += RY * d0;
                az[r*4 + m + 1][1] += RY * d1;
            }
        }
    }
    // split to bf16 hi/lo, pack: k_local = cg*24 + e*12 + j (contiguous 24 ush)
    unsigned int uh[12], ul[12];
    #pragma unroll
    for (int e = 0; e < 2; e++)
        #pragma unroll
        for (int j2 = 0; j2 < 6; j2++) {
            float a0 = az[2*j2][e], a1 = az[2*j2+1][e];
            unsigned int b0 = __float_as_uint(a0), b1 = __float_as_uint(a1);
            float r0 = a0 - __uint_as_float(b0 & 0xFFFF0000u);
            float r1 = a1 - __uint_as_float(b1 & 0xFFFF0000u);
            uh[e*6 + j2] = (b0 >> 16) | ((b1 >> 16) << 16);
            ul[e*6 + j2] = (__float_as_uint(r0) >> 16) | ((__float_as_uint(r1) >> 16) << 16);
        }
    int base = vox * 104 + cg * 24;        // ushort offset, 16B-aligned pieces
    *reinterpret_cast<u32x4*>(zch + base)      = (u32x4){uh[0], uh[1], uh[2],  uh[3]};
    *reinterpret_cast<u32x4*>(zch + base + 8)  = (u32x4){uh[4], uh[5], uh[6],  uh[7]};
    *reinterpret_cast<u32x4*>(zch + base + 16) = (u32x4){uh[8], uh[9], uh[10], uh[11]};
    *reinterpret_cast<u32x4*>(zcl + base)      = (u32x4){ul[0], ul[1], ul[2],  ul[3]};
    *reinterpret_cast<u32x4*>(zcl + base + 8)  = (u32x4){ul[4], ul[5], ul[6],  ul[7]};
    *reinterpret_cast<u32x4*>(zcl + base + 16) = (u32x4){ul[8], ul[9], ul[10], ul[11]};
}

__global__ __attribute__((amdgpu_flat_work_group_size(512, 512), amdgpu_waves_per_eu(4)))
void fused_conv(
    const float* __restrict__ xin, const unsigned short* __restrict__ Wh,
    const unsigned short* __restrict__ Wl, float* __restrict__ xout)
{
    __shared__ float smem[19072];                       // 76,288 B -> 2 blocks/CU
    unsigned short* zc = reinterpret_cast<unsigned short*>(smem + 5760);
    int t = threadIdx.x;
    int wv = t >> 6, l = t & 63;
    bool Aw = wv < 4;
    int vox = t & 63, cg = wv & 3;                      // stage-A decode
    int lr = l & 15, lk = l >> 4;                       // MFMA lane decode
    int rowbase = (wv & 3) * 16;                        // stage-B rows
    int brow = rowbase + lr;
    int bid = blockIdx.x;
    int dt = (bid >> 5) << 1;
    int h0 = ((bid >> 2) & 7) << 2;
    int w0 = (bid & 3) << 3;

    // steady-state halo slots (B-threads): 1152 float4 / 256 thr = 5 (guarded)
    int go5[5], lo5[5];
    if (!Aw) {
        #pragma unroll
        for (int q = 0; q < 5; q++) {
            int i = (t - 256) + q * 256;
            if (i < 1152) halo_slot(i, dt, h0, w0, go5[q], lo5[q]);
            else { go5[q] = -2; lo5[q] = 0; }
        }
    }

    // prologue: halo chunk 0 (all threads)
    #pragma unroll
    for (int q = 0; q < 3; q++) {
        int i = t + q * 512;
        if (i < 1152) {
            int go, lo; halo_slot(i, dt, h0, w0, go, lo);
            float4 v = (go >= 0) ? *reinterpret_cast<const float4*>(xin + go)
                                 : make_float4(0.f, 0.f, 0.f, 0.f);
            *reinterpret_cast<float4*>(smem + lo) = v;
        }
    }
    __syncthreads();

    const f32x4 fzero = {0.f, 0.f, 0.f, 0.f};
    f32x4 acc0 = fzero, acc1 = fzero, acc2 = fzero,
          acc3 = fzero, acc4 = fzero, acc5 = fzero;

    for (int cc = 0; cc <= 10; cc++) {
        // P1: A(cc) || B(cc-1)  -- stage B inlined, named accumulators
        if (Aw) {
            if (cc < 10) {
                unsigned short* zb = zc + (cc & 1) * 13312;
                stageA(smem, zb, zb + 6656, vox, cg);
            }
        } else if (cc >= 1) {
            int c10 = cc - 1;
            const unsigned short* zb  = zc + (c10 & 1) * 13312;
            const unsigned short* zh  = zb + brow * 104 + lk * 8;
            const unsigned short* zl  = zh + 6656;
            const unsigned short* wb  = Wh + lr * 960 + c10 * 96 + lk * 8;
            const unsigned short* wbl = Wl + lr * 960 + c10 * 96 + lk * 8;
            #pragma unroll
            for (int ks = 0; ks < 3; ks++) {
                bf16x8 ah = *reinterpret_cast<const bf16x8*>(zh + ks * 32);
                bf16x8 al = *reinterpret_cast<const bf16x8*>(zl + ks * 32);
#define MFMA_NT(A, NT) { \
                bf16x8 bh = *reinterpret_cast<const bf16x8*>(wb  + (NT) * 15360 + ks * 32); \
                bf16x8 bl = *reinterpret_cast<const bf16x8*>(wbl + (NT) * 15360 + ks * 32); \
                A = __builtin_amdgcn_mfma_f32_16x16x32_bf16(ah, bh, A, 0, 0, 0); \
                A = __builtin_amdgcn_mfma_f32_16x16x32_bf16(al, bh, A, 0, 0, 0); \
                A = __builtin_amdgcn_mfma_f32_16x16x32_bf16(ah, bl, A, 0, 0, 0); }
                MFMA_NT(acc0, 0) MFMA_NT(acc1, 1) MFMA_NT(acc2, 2)
                MFMA_NT(acc3, 3) MFMA_NT(acc4, 4) MFMA_NT(acc5, 5)
#undef MFMA_NT
            }
        }
        __syncthreads();
        // P2: B-threads load halo chunk cc+1 directly to LDS (no reg prefetch)
        if (!Aw && cc < 9) {
            int chof = (cc + 1) * 8;
            #pragma unroll
            for (int q = 0; q < 5; q++)
                if (go5[q] != -2) {
                    float4 v = (go5[q] >= 0)
                             ? *reinterpret_cast<const float4*>(xin + go5[q] + chof)
                             : make_float4(0.f, 0.f, 0.f, 0.f);
                    *reinterpret_cast<float4*>(smem + lo5[q]) = v;
                }
        }
        __syncthreads();
    }

    // epilogue: y -> gate -> store (reuse smem as y[64][98])
    float* y = smem;
    if (!Aw) {
        // C/D layout: col = lane&15, row = (lane>>4)*4 + reg
#define WR_NT(A, NT) { \
        _Pragma("unroll") \
        for (int r = 0; r < 4; r++) \
            y[(rowbase + lk * 4 + r) * 98 + (NT) * 16 + lr] = A[r]; }
        WR_NT(acc0, 0) WR_NT(acc1, 1) WR_NT(acc2, 2)
        WR_NT(acc3, 3) WR_NT(acc4, 4) WR_NT(acc5, 5)
#undef WR_NT
    }
    __syncthreads();
    #pragma unroll
    for (int it = 0; it < 10; it++) {
        int idx = t + it * 512;
        int vr = idx / 80, c = idx - vr * 80;
        int gd = dt + (vr >> 5), gh = h0 + ((vr >> 3) & 3), gw = w0 + (vr & 7);
        const float* yr = y + vr * 98;
        float val;
        if (c < 32) val = fmaxf(yr[c], 0.f);
        else {
            int q = c - 32;
            float g = 1.f / (1.f + __expf(-yr[32 + q / 3]));
            val = yr[48 + q] * g;
        }
        xout[(size_t)(((gd << 5) + gh) * 32 + gw) * 80 + c] = val;
    }
}

// ---------------------------------------------------------------- Final head (nontemporal stores)
__global__ __launch_bounds__(256) void final_k(
    const float* __restrict__ x2, const float* __restrict__ wls,
    const float* __restrict__ wlv, const float* __restrict__ wpos,
    float* __restrict__ out)
{
    __shared__ float xv[16 * 81];
    __shared__ float coeff[16 * 161];
    __shared__ float s_wls[512];
    __shared__ float s_wlv[768];
    int t = threadIdx.x;
    int bid = blockIdx.x;
    int cw0 = (bid & 1) * 16;
    int ch  = (bid >> 1) & 31;
    int cd  = bid >> 6;
    float wp = wpos[0];
    {
        int base = ((cd * 32 + ch) * 32 + cw0) * 80;
        #pragma unroll
        for (int i = t; i < 1280; i += 256) {
            int vi = i / 80, c = i % 80;
            xv[vi * 81 + c] = x2[base + i];
        }
        for (int i = t; i < 512; i += 256) s_wls[i] = wls[i];
        for (int i = t; i < 768; i += 256) s_wlv[i] = wlv[i];
    }
    __syncthreads();
    {
        int vi = t >> 4, j = t & 15;
        const float* xp = xv + vi * 81;
        float* cf = coeff + vi * 161;
        #pragma unroll
        for (int l = 0; l < 10; l++) {
            int q = l * 16 + j;
            float sum = 0.f;
            if (q < 96) {
                int o = q / 3, m = q % 3;
                #pragma unroll
                for (int c = 0; c < 16; c++) sum += xp[32 + c * 3 + m] * s_wls[c * 32 + o];
            } else if (q < 112) {
                int o = q - 96;
                #pragma unroll
                for (int c = 0; c < 32; c++) sum += xp[c] * s_wlv[c * 16 + o];
            } else {
                int q2 = q - 112; int o = q2 / 3, m = q2 % 3;
                #pragma unroll
                for (int c = 0; c < 16; c++) sum += xp[32 + c * 3 + m] * s_wlv[(32 + c) * 16 + o];
            }
            cf[q] = sum;
        }
    }
    __syncthreads();
    const float scale = 0.14433756729740643f;
    #pragma unroll
    for (int f01 = 0; f01 < 4; f01++) {
        int fd = 2 * cd + (f01 >> 1), fh = 2 * ch + (f01 & 1);
        float p0 = wp * (float)(cd + (f01 >> 1) - 16);
        float p1 = wp * (float)(ch + (f01 & 1) - 16);
        size_t obase = (size_t)((fd * 64 + fh) * 64 + cw0 * 2) * 80;
        #pragma unroll
        for (int it = 0; it < 3; it++) {
            int idx4 = it * 256 + t;
            if (idx4 < 640) {
                int base = idx4 * 4;
                int fwl = base / 80, c0 = base - fwl * 80;
                int vi = fwl >> 1;
                float p2 = wp * (float)(cw0 + vi + (fwl & 1) - 16);
                const float* cf = coeff + vi * 161;
                float vv[4];
                if (c0 < 32) {
                    #pragma unroll
                    for (int e = 0; e < 4; e++) {
                        int c = c0 + e;
                        vv[e] = cf[c * 3] * p0 + cf[c * 3 + 1] * p1 + cf[c * 3 + 2] * p2;
                    }
                } else {
                    #pragma unroll
                    for (int e = 0; e < 4; e++) {
                        int q = c0 - 32 + e, o = q / 3, m = q - o * 3;
                        float A = cf[96 + o];
                        const float* w2 = cf + 112 + o * 3;
                        float pm, crm;
                        if (m == 0)      { pm = p0; crm = w2[1] * p2 - w2[2] * p1; }
                        else if (m == 1) { pm = p1; crm = w2[2] * p0 - w2[0] * p2; }
                        else             { pm = p2; crm = w2[0] * p1 - w2[1] * p0; }
                        vv[e] = A * pm + crm * 0.7071067811865476f;
                    }
                }
                f32x4 o4 = {vv[0]*scale, vv[1]*scale, vv[2]*scale, vv[3]*scale};
                __builtin_nontemporal_store(o4, reinterpret_cast<f32x4*>(out + obase + base));
            }
        }
    }
}

// ----------------------------------------------------------------
extern "C" void kernel_launch(void* const* d_in, const int* in_sizes, int n_in,
                              void* d_out, int out_size, void* d_ws, size_t ws_size,
                              hipStream_t stream)
{
    const float* x    = (const float*)d_in[0];
    const float* wpos = (const float*)d_in[11];
    const float* wls  = (const float*)d_in[12];
    const float* wlv  = (const float*)d_in[13];
    float* out = (float*)d_out;
    float* ws  = (float*)d_ws;

    float* W   = ws + 1024;                 // 184320 fp32
    unsigned short* Wh = (unsigned short*)(ws + 1024 + 184320);   // 184320 ushorts
    unsigned short* Wl = Wh + 184320;                              // 184320 ushorts
    float* x1  = ws + 1024 + 184320 + 184320;
    float* x2  = x1 + 2621440;

    build_W<<<720, 256, 0, stream>>>(W,
        (const float*)d_in[1], (const float*)d_in[2], (const float*)d_in[3],
        (const float*)d_in[4], (const float*)d_in[5],
        (const float*)d_in[6], (const float*)d_in[7], (const float*)d_in[8],
        (const float*)d_in[9], (const float*)d_in[10]);
    build_Wc<<<720, 256, 0, stream>>>(W, Wh, Wl);

    fused_conv<<<512, 512, 0, stream>>>(x,  Wh,         Wl,         x1);
    fused_conv<<<512, 512, 0, stream>>>(x1, Wh + 92160, Wl + 92160, x2);
    final_k<<<2048, 256, 0, stream>>>(x2, wls, wlv, wpos, out);
}

// Round 13
// 430.244 us; speedup vs baseline: 1.4345x; 1.4178x over previous
//
#include <hip/hip_runtime.h>
#include <math.h>

// x: [1,32,32,32,80] fp32 (80 = 32 scalars + 16 vec*3)
// conv: low-rank kernel basis 12 = 3 radial * {1, Yd, Yh, Yw}
// FUSED conv, producer/consumer: 512-thr blocks (8 waves), 64-voxel tile (2,4,8),
//   2 blocks/CU (LDS 76.3 KB).  10 chunks of 8 ci.  Fixed roles:
//   waves 0-3 = stage A (tap-pair VALU -> zc[c&1]);  waves 4-7 = stage B
//   (split-bf16 MFMA on zc[(c-1)&1], NAMED accumulators inlined at one site)
//   + direct halo load->LDS in P2.
//   __launch_bounds__(512,2): the attribute form pinned VGPR=64 and spilled
//   ~280 MB/dispatch (rounds 9-11); launch_bounds raised budget in round 3.
// out: [1,64,64,64,80] fp32

typedef __attribute__((ext_vector_type(8))) short bf16x8;
typedef __attribute__((ext_vector_type(4))) float f32x4;
typedef __attribute__((ext_vector_type(4))) unsigned int u32x4;

__device__ __forceinline__ int eps3(int a, int m, int b) {
    if (a == b || a == m || m == b) return 0;
    return ((a==0&&m==1&&b==2)||(a==1&&m==2&&b==0)||(a==2&&m==0&&b==1)) ? 1 : -1;
}

// ---------------------------------------------------------------- constexpr tap table
// halo layout: pos = hd*96 + hh*12 + hw  (6x8x12), row stride 10 floats (8 ci + 2 pad)
struct TapTab {
    int   op[40];        // float-offset, positive rep
    float R[40][3];
    float RY[40][9];
    float Rc[3];
};
constexpr float cexpf_(float x) {
    float y = x * (1.f/16.f);
    float s = 1.f + y*(1.f + y*(0.5f + y*((1.f/6.f) + y*((1.f/24.f) + y*(1.f/120.f)))));
    s *= s; s *= s; s *= s; s *= s;
    return s;
}
constexpr float csqrtf_(float x) {
    float g = x > 1.f ? x : 1.f;
    for (int i = 0; i < 40; i++) g = 0.5f*(g + x/g);
    return g;
}
constexpr TapTab make_taps() {
    TapTab T{};
    int idx = 0;
    for (int t = 0; t < 125; t++) {
        int td = t/25 - 2, th = (t/5)%5 - 2, tw = t%5 - 2;
        int n2 = td*td + th*th + tw*tw;
        if (t == 62) {
            for (int r = 0; r < 3; r++) {
                float tt = (0.f - 1.25f*(float)r) * 0.8f;
                T.Rc[r] = cexpf_(-tt*tt);
            }
            continue;
        }
        bool active = n2 <= 6;
        bool pos = (td>0) || (td==0 && th>0) || (td==0 && th==0 && tw>0);
        if (!(active && pos)) continue;
        T.op[idx] = (td*96 + th*12 + tw) * 10;
        float norm = csqrtf_((float)n2);
        float comp[3] = {(float)td, (float)th, (float)tw};
        for (int r = 0; r < 3; r++) {
            float tt = (norm - 1.25f*(float)r) * 0.8f;
            float R = cexpf_(-tt*tt);
            T.R[idx][r] = R;
            for (int m = 0; m < 3; m++)
                T.RY[idx][r*3+m] = R * 1.7320508075688772f * comp[m] / norm;
        }
        idx++;
    }
    return T;
}
__device__ constexpr TapTab TT = make_taps();

// ---------------------------------------------------------------- W matrices (fp32 source)
__global__ void build_W(float* __restrict__ W,
    const float* __restrict__ ss1, const float* __restrict__ sv1,
    const float* __restrict__ vs1, const float* __restrict__ vv01, const float* __restrict__ vv11,
    const float* __restrict__ ss2, const float* __restrict__ sv2,
    const float* __restrict__ vs2, const float* __restrict__ vv02, const float* __restrict__ vv12)
{
    int idx = threadIdx.x + blockIdx.x * 256;
    if (idx >= 184320) return;
    int conv = idx / 92160;
    int rem  = idx % 92160;
    int j  = rem / 7680;
    int ci = (rem / 96) % 80;
    int co = rem % 96;
    int r = j >> 2, al = j & 3;
    const float* ss  = conv ? ss2  : ss1;
    const float* sv  = conv ? sv2  : sv1;
    const float* vs  = conv ? vs2  : vs1;
    const float* vv0 = conv ? vv02 : vv01;
    const float* vv1 = conv ? vv12 : vv11;
    float val = 0.f;
    if (ci < 32) {
        if (co < 48) { if (al == 0) val = ss[(r*32 + ci)*48 + co]; }
        else {
            int o = (co - 48) / 3, m = (co - 48) % 3;
            if (al == m + 1) val = sv[(r*32 + ci)*16 + o];
        }
    } else {
        int i = (ci - 32) / 3, a = (ci - 32) % 3;
        if (co < 48) { if (al == a + 1) val = vs[(r*16 + i)*48 + co] * 0.5773502691896258f; }
        else {
            int o = (co - 48) / 3, b = (co - 48) % 3;
            if (al == 0) { if (a == b) val = vv0[(r*16 + i)*16 + o]; }
            else {
                int e = eps3(a, al - 1, b);
                if (e) val = vv1[(r*16 + i)*16 + o] * (float)e * 0.7071067811865476f;
            }
        }
    }
    W[idx] = val;
}

// ---------------------------------------------------------------- W split bf16 hi/lo, chunk-permuted
// Wc[conv][co][k'],  k' = c10*96 + cg*24 + e*12 + j;  ci = c10*8 + cg*2 + e;  k = j*80+ci
__global__ void build_Wc(const float* __restrict__ W,
                         unsigned short* __restrict__ Wh, unsigned short* __restrict__ Wl)
{
    int idx = threadIdx.x + blockIdx.x * 256;    // over 2*96*960
    if (idx >= 184320) return;
    int conv = idx / 92160, rem = idx % 92160;
    int co = rem / 960, kp = rem % 960;
    int c10 = kp / 96, r2 = kp % 96;
    int cg = r2 / 24, r3 = r2 % 24;
    int e = r3 / 12, j = r3 % 12;
    int ci = c10 * 8 + cg * 2 + e;
    int k = j * 80 + ci;
    float w = W[conv * 92160 + k * 96 + co];
    unsigned int u = __float_as_uint(w);
    unsigned int hib = (u + 0x7FFFu + ((u >> 16) & 1u)) & 0xFFFF0000u;  // RNE bf16
    float res = w - __uint_as_float(hib);
    unsigned int v = __float_as_uint(res);
    unsigned int lob = (v + 0x7FFFu + ((v >> 16) & 1u)) >> 16;
    Wh[idx] = (unsigned short)(hib >> 16);
    Wl[idx] = (unsigned short)lob;
}

// ---------------------------------------------------------------- fused conv
// LDS map (floats): [0,5760) halo[576 pos][10]
//                   ushort region at +5760 fl: zc 2 bufs x {hi[64][104], lo[64][104]}
//                   buf b: base b*13312 ush; hi +0, lo +6656.   Total 76288 B.
// epilogue reuses floats [0, 6272) as y[64][98]

__device__ __forceinline__ void halo_slot(int i, int dt, int h0, int w0, int& go, int& lo) {
    int pos = i >> 1, half = i & 1;
    int hd = pos / 96, rm = pos - hd * 96;
    int hh = rm / 12, hw = rm - hh * 12;
    int gd = dt + hd - 2, gh = h0 + hh - 2, gw = w0 + hw - 2;
    go = (gd >= 0 && gd < 32 && gh >= 0 && gh < 32 && gw >= 0 && gw < 32)
       ? (((gd << 5) + gh) * 32 + gw) * 80 + half * 4 : -1;
    lo = pos * 10 + half * 4;
}

__device__ __forceinline__ void stageA(
    const float* __restrict__ smem, unsigned short* __restrict__ zch,
    unsigned short* __restrict__ zcl, int vox, int cg)
{
    int pos = ((vox >> 5) + 2) * 96 + (((vox >> 3) & 3) + 2) * 12 + (vox & 7) + 2;
    const float* xpb = smem + pos * 10 + 2 * cg - 2180;   // bias: max |op| = 2180
    float az[12][2];
    #pragma unroll
    for (int j = 0; j < 12; j++) { az[j][0] = 0.f; az[j][1] = 0.f; }
    {   // center
        float2 xc = *reinterpret_cast<const float2*>(xpb + 2180);
        #pragma unroll
        for (int r = 0; r < 3; r++) {
            float R = TT.Rc[r];
            az[r*4][0] += R * xc.x; az[r*4][1] += R * xc.y;
        }
    }
    #pragma unroll
    for (int p = 0; p < 40; p++) {
        float2 xa = *reinterpret_cast<const float2*>(xpb + (2180 + TT.op[p]));
        float2 xb = *reinterpret_cast<const float2*>(xpb + (2180 - TT.op[p]));
        float s0 = xa.x + xb.x, s1 = xa.y + xb.y;
        float d0 = xa.x - xb.x, d1 = xa.y - xb.y;
        #pragma unroll
        for (int r = 0; r < 3; r++) {
            float R = TT.R[p][r];
            az[r*4][0] += R * s0; az[r*4][1] += R * s1;
            #pragma unroll
            for (int m = 0; m < 3; m++) {
                float RY = TT.RY[p][r*3+m];
                az[r*4 + m + 1][0] += RY * d0;
                az[r*4 + m + 1][1] += RY * d1;
            }
        }
    }
    // split to bf16 hi/lo, pack: k_local = cg*24 + e*12 + j (contiguous 24 ush)
    unsigned int uh[12], ul[12];
    #pragma unroll
    for (int e = 0; e < 2; e++)
        #pragma unroll
        for (int j2 = 0; j2 < 6; j2++) {
            float a0 = az[2*j2][e], a1 = az[2*j2+1][e];
            unsigned int b0 = __float_as_uint(a0), b1 = __float_as_uint(a1);
            float r0 = a0 - __uint_as_float(b0 & 0xFFFF0000u);
            float r1 = a1 - __uint_as_float(b1 & 0xFFFF0000u);
            uh[e*6 + j2] = (b0 >> 16) | ((b1 >> 16) << 16);
            ul[e*6 + j2] = (__float_as_uint(r0) >> 16) | ((__float_as_uint(r1) >> 16) << 16);
        }
    int base = vox * 104 + cg * 24;        // ushort offset, 16B-aligned pieces
    *reinterpret_cast<u32x4*>(zch + base)      = (u32x4){uh[0], uh[1], uh[2],  uh[3]};
    *reinterpret_cast<u32x4*>(zch + base + 8)  = (u32x4){uh[4], uh[5], uh[6],  uh[7]};
    *reinterpret_cast<u32x4*>(zch + base + 16) = (u32x4){uh[8], uh[9], uh[10], uh[11]};
    *reinterpret_cast<u32x4*>(zcl + base)      = (u32x4){ul[0], ul[1], ul[2],  ul[3]};
    *reinterpret_cast<u32x4*>(zcl + base + 8)  = (u32x4){ul[4], ul[5], ul[6],  ul[7]};
    *reinterpret_cast<u32x4*>(zcl + base + 16) = (u32x4){ul[8], ul[9], ul[10], ul[11]};
}

__global__ __launch_bounds__(512, 2)
void fused_conv(
    const float* __restrict__ xin, const unsigned short* __restrict__ Wh,
    const unsigned short* __restrict__ Wl, float* __restrict__ xout)
{
    __shared__ float smem[19072];                       // 76,288 B -> 2 blocks/CU
    unsigned short* zc = reinterpret_cast<unsigned short*>(smem + 5760);
    int t = threadIdx.x;
    int wv = t >> 6, l = t & 63;
    bool Aw = wv < 4;
    int vox = t & 63, cg = wv & 3;                      // stage-A decode
    int lr = l & 15, lk = l >> 4;                       // MFMA lane decode
    int rowbase = (wv & 3) * 16;                        // stage-B rows
    int brow = rowbase + lr;
    int bid = blockIdx.x;
    int dt = (bid >> 5) << 1;
    int h0 = ((bid >> 2) & 7) << 2;
    int w0 = (bid & 3) << 3;

    // steady-state halo slots (B-threads): 1152 float4 / 256 thr = 5 (guarded)
    int go5[5], lo5[5];
    if (!Aw) {
        #pragma unroll
        for (int q = 0; q < 5; q++) {
            int i = (t - 256) + q * 256;
            if (i < 1152) halo_slot(i, dt, h0, w0, go5[q], lo5[q]);
            else { go5[q] = -2; lo5[q] = 0; }
        }
    }

    // prologue: halo chunk 0 (all threads)
    #pragma unroll
    for (int q = 0; q < 3; q++) {
        int i = t + q * 512;
        if (i < 1152) {
            int go, lo; halo_slot(i, dt, h0, w0, go, lo);
            float4 v = (go >= 0) ? *reinterpret_cast<const float4*>(xin + go)
                                 : make_float4(0.f, 0.f, 0.f, 0.f);
            *reinterpret_cast<float4*>(smem + lo) = v;
        }
    }
    __syncthreads();

    const f32x4 fzero = {0.f, 0.f, 0.f, 0.f};
    f32x4 acc0 = fzero, acc1 = fzero, acc2 = fzero,
          acc3 = fzero, acc4 = fzero, acc5 = fzero;

    for (int cc = 0; cc <= 10; cc++) {
        // P1: A(cc) || B(cc-1)  -- stage B inlined, named accumulators
        if (Aw) {
            if (cc < 10) {
                unsigned short* zb = zc + (cc & 1) * 13312;
                stageA(smem, zb, zb + 6656, vox, cg);
            }
        } else if (cc >= 1) {
            int c10 = cc - 1;
            const unsigned short* zb  = zc + (c10 & 1) * 13312;
            const unsigned short* zh  = zb + brow * 104 + lk * 8;
            const unsigned short* zl  = zh + 6656;
            const unsigned short* wb  = Wh + lr * 960 + c10 * 96 + lk * 8;
            const unsigned short* wbl = Wl + lr * 960 + c10 * 96 + lk * 8;
            #pragma unroll
            for (int ks = 0; ks < 3; ks++) {
                bf16x8 ah = *reinterpret_cast<const bf16x8*>(zh + ks * 32);
                bf16x8 al = *reinterpret_cast<const bf16x8*>(zl + ks * 32);
#define MFMA_NT(A, NT) { \
                bf16x8 bh = *reinterpret_cast<const bf16x8*>(wb  + (NT) * 15360 + ks * 32); \
                bf16x8 bl = *reinterpret_cast<const bf16x8*>(wbl + (NT) * 15360 + ks * 32); \
                A = __builtin_amdgcn_mfma_f32_16x16x32_bf16(ah, bh, A, 0, 0, 0); \
                A = __builtin_amdgcn_mfma_f32_16x16x32_bf16(al, bh, A, 0, 0, 0); \
                A = __builtin_amdgcn_mfma_f32_16x16x32_bf16(ah, bl, A, 0, 0, 0); }
                MFMA_NT(acc0, 0) MFMA_NT(acc1, 1) MFMA_NT(acc2, 2)
                MFMA_NT(acc3, 3) MFMA_NT(acc4, 4) MFMA_NT(acc5, 5)
#undef MFMA_NT
            }
        }
        __syncthreads();
        // P2: B-threads load halo chunk cc+1 directly to LDS (no reg prefetch)
        if (!Aw && cc < 9) {
            int chof = (cc + 1) * 8;
            #pragma unroll
            for (int q = 0; q < 5; q++)
                if (go5[q] != -2) {
                    float4 v = (go5[q] >= 0)
                             ? *reinterpret_cast<const float4*>(xin + go5[q] + chof)
                             : make_float4(0.f, 0.f, 0.f, 0.f);
                    *reinterpret_cast<float4*>(smem + lo5[q]) = v;
                }
        }
        __syncthreads();
    }

    // epilogue: y -> gate -> store (reuse smem as y[64][98])
    float* y = smem;
    if (!Aw) {
        // C/D layout: col = lane&15, row = (lane>>4)*4 + reg
#define WR_NT(A, NT) { \
        _Pragma("unroll") \
        for (int r = 0; r < 4; r++) \
            y[(rowbase + lk * 4 + r) * 98 + (NT) * 16 + lr] = A[r]; }
        WR_NT(acc0, 0) WR_NT(acc1, 1) WR_NT(acc2, 2)
        WR_NT(acc3, 3) WR_NT(acc4, 4) WR_NT(acc5, 5)
#undef WR_NT
    }
    __syncthreads();
    #pragma unroll
    for (int it = 0; it < 10; it++) {
        int idx = t + it * 512;
        int vr = idx / 80, c = idx - vr * 80;
        int gd = dt + (vr >> 5), gh = h0 + ((vr >> 3) & 3), gw = w0 + (vr & 7);
        const float* yr = y + vr * 98;
        float val;
        if (c < 32) val = fmaxf(yr[c], 0.f);
        else {
            int q = c - 32;
            float g = 1.f / (1.f + __expf(-yr[32 + q / 3]));
            val = yr[48 + q] * g;
        }
        xout[(size_t)(((gd << 5) + gh) * 32 + gw) * 80 + c] = val;
    }
}

// ---------------------------------------------------------------- Final head (nontemporal stores)
__global__ __launch_bounds__(256) void final_k(
    const float* __restrict__ x2, const float* __restrict__ wls,
    const float* __restrict__ wlv, const float* __restrict__ wpos,
    float* __restrict__ out)
{
    __shared__ float xv[16 * 81];
    __shared__ float coeff[16 * 161];
    __shared__ float s_wls[512];
    __shared__ float s_wlv[768];
    int t = threadIdx.x;
    int bid = blockIdx.x;
    int cw0 = (bid & 1) * 16;
    int ch  = (bid >> 1) & 31;
    int cd  = bid >> 6;
    float wp = wpos[0];
    {
        int base = ((cd * 32 + ch) * 32 + cw0) * 80;
        #pragma unroll
        for (int i = t; i < 1280; i += 256) {
            int vi = i / 80, c = i % 80;
            xv[vi * 81 + c] = x2[base + i];
        }
        for (int i = t; i < 512; i += 256) s_wls[i] = wls[i];
        for (int i = t; i < 768; i += 256) s_wlv[i] = wlv[i];
    }
    __syncthreads();
    {
        int vi = t >> 4, j = t & 15;
        const float* xp = xv + vi * 81;
        float* cf = coeff + vi * 161;
        #pragma unroll
        for (int l = 0; l < 10; l++) {
            int q = l * 16 + j;
            float sum = 0.f;
            if (q < 96) {
                int o = q / 3, m = q % 3;
                #pragma unroll
                for (int c = 0; c < 16; c++) sum += xp[32 + c * 3 + m] * s_wls[c * 32 + o];
            } else if (q < 112) {
                int o = q - 96;
                #pragma unroll
                for (int c = 0; c < 32; c++) sum += xp[c] * s_wlv[c * 16 + o];
            } else {
                int q2 = q - 112; int o = q2 / 3, m = q2 % 3;
                #pragma unroll
                for (int c = 0; c < 16; c++) sum += xp[32 + c * 3 + m] * s_wlv[(32 + c) * 16 + o];
            }
            cf[q] = sum;
        }
    }
    __syncthreads();
    const float scale = 0.14433756729740643f;
    #pragma unroll
    for (int f01 = 0; f01 < 4; f01++) {
        int fd = 2 * cd + (f01 >> 1), fh = 2 * ch + (f01 & 1);
        float p0 = wp * (float)(cd + (f01 >> 1) - 16);
        float p1 = wp * (float)(ch + (f01 & 1) - 16);
        size_t obase = (size_t)((fd * 64 + fh) * 64 + cw0 * 2) * 80;
        #pragma unroll
        for (int it = 0; it < 3; it++) {
            int idx4 = it * 256 + t;
            if (idx4 < 640) {
                int base = idx4 * 4;
                int fwl = base / 80, c0 = base - fwl * 80;
                int vi = fwl >> 1;
                float p2 = wp * (float)(cw0 + vi + (fwl & 1) - 16);
                const float* cf = coeff + vi * 161;
                float vv[4];
                if (c0 < 32) {
                    #pragma unroll
                    for (int e = 0; e < 4; e++) {
                        int c = c0 + e;
                        vv[e] = cf[c * 3] * p0 + cf[c * 3 + 1] * p1 + cf[c * 3 + 2] * p2;
                    }
                } else {
                    #pragma unroll
                    for (int e = 0; e < 4; e++) {
                        int q = c0 - 32 + e, o = q / 3, m = q - o * 3;
                        float A = cf[96 + o];
                        const float* w2 = cf + 112 + o * 3;
                        float pm, crm;
                        if (m == 0)      { pm = p0; crm = w2[1] * p2 - w2[2] * p1; }
                        else if (m == 1) { pm = p1; crm = w2[2] * p0 - w2[0] * p2; }
                        else             { pm = p2; crm = w2[0] * p1 - w2[1] * p0; }
                        vv[e] = A * pm + crm * 0.7071067811865476f;
                    }
                }
                f32x4 o4 = {vv[0]*scale, vv[1]*scale, vv[2]*scale, vv[3]*scale};
                __builtin_nontemporal_store(o4, reinterpret_cast<f32x4*>(out + obase + base));
            }
        }
    }
}

// ----------------------------------------------------------------
extern "C" void kernel_launch(void* const* d_in, const int* in_sizes, int n_in,
                              void* d_out, int out_size, void* d_ws, size_t ws_size,
                              hipStream_t stream)
{
    const float* x    = (const float*)d_in[0];
    const float* wpos = (const float*)d_in[11];
    const float* wls  = (const float*)d_in[12];
    const float* wlv  = (const float*)d_in[13];
    float* out = (float*)d_out;
    float* ws  = (float*)d_ws;

    float* W   = ws + 1024;                 // 184320 fp32
    unsigned short* Wh = (unsigned short*)(ws + 1024 + 184320);   // 184320 ushorts
    unsigned short* Wl = Wh + 184320;                              // 184320 ushorts
    float* x1  = ws + 1024 + 184320 + 184320;
    float* x2  = x1 + 2621440;

    build_W<<<720, 256, 0, stream>>>(W,
        (const float*)d_in[1], (const float*)d_in[2], (const float*)d_in[3],
        (const float*)d_in[4], (const float*)d_in[5],
        (const float*)d_in[6], (const float*)d_in[7], (const float*)d_in[8],
        (const float*)d_in[9], (const float*)d_in[10]);
    build_Wc<<<720, 256, 0, stream>>>(W, Wh, Wl);

    fused_conv<<<512, 512, 0, stream>>>(x,  Wh,         Wl,         x1);
    fused_conv<<<512, 512, 0, stream>>>(x1, Wh + 92160, Wl + 92160, x2);
    final_k<<<2048, 256, 0, stream>>>(x2, wls, wlv, wpos, out);
}